// Round 5
// baseline (88.245 us; speedup 1.0000x reference)
//
#include <hip/hip_runtime.h>

#define SEQ   512
#define BATCH 256
#define NH    7   // helper waves (waves 1..7)

// Uniform-index lane broadcast via v_readlane (index wave-uniform, may be runtime).
__device__ __forceinline__ float bcast_f(float v, int srcLane) {
    return __int_as_float(__builtin_amdgcn_readlane(__float_as_int(v), srcLane));
}
// gfx950: v_log_f32 is log2, v_exp_f32 is exp2.
__device__ __forceinline__ float flog2(float x) { return __builtin_amdgcn_logf(x); }
__device__ __forceinline__ float fexp2(float x) { return __builtin_amdgcn_exp2f(x); }

// One block (512 threads = 8 waves) per batch column.
// All waves hold a private register copy of all 512 pre-scaled timestamps
// (x[8], row i = lane + 64r). Helpers read published expm once per phase as a
// coalesced vector and broadcast per-column via v_readlane -- the inner loops
// touch NO memory. Wave 0 runs the serial diagonal with a 3-dep chain:
//   d^p = exp2(-a*L) * exp2((-c*L)*em),  L = log2(max(dx,1)) precomputed
// Maskless diag trick: lanes i <= jl give L=0 -> term = 1.0 exactly; the carry
// readlane at step jl happens before lane jl's first contamination; subtract
// (64-lane) once at the end.
__global__ void __launch_bounds__(512, 1)
act_r_kernel(const float* __restrict__ sp, const float* __restrict__ w,
             float* __restrict__ out) {
    __shared__ float x_lds[SEQ];
    __shared__ float expm_lds[SEQ];
    __shared__ float part_lds[NH][8][64];   // [helper][row block][lane]

    const int b    = blockIdx.x;
    const int tid  = threadIdx.x;
    const int wid  = tid >> 6;
    const int lane = tid & 63;

    const float a   = w[0];
    const float c   = w[1];
    const float s   = w[2];
    const float tau = w[3];
    const float h   = w[4];
    const float scale = 86400.0f * h;

    for (int k = tid; k < NH * 8 * 64; k += 512) ((float*)part_lds)[k] = 0.0f;
    x_lds[tid] = sp[tid * BATCH + b] * scale;
    __syncthreads();

    // Private register copy of all 512 x values (coalesced LDS reads, once).
    float x[8];
#pragma unroll
    for (int r = 0; r < 8; ++r) x[r] = x_lds[(r << 6) | lane];

    const float inv_ln2 = 1.4426950408889634f;
    const float k1 = tau / s * inv_ln2;
    const float k2 = 1.0f / s;

    float clean = 0.0f;   // wave0: deferred-epilogue value of previous block
    float evec  = 0.0f;   // helpers: expm of column block J-1 (lane jc holds col jc)

    for (int J = 0; J < 8; ++J) {
        if (J > 0) evec = expm_lds[((J - 1) << 6) | lane];  // one coalesced read/phase

        if (wid > 0) {
            // ---- phase A: panel (col block J-1 -> row block J), register-only
            if (J > 0) {
                const float xr = x[J];
                float pacc = 0.0f;
                for (int jc = wid - 1; jc < 64; jc += NH) {
                    const float em = bcast_f(evec, jc);
                    const float xj = bcast_f(x[J - 1], jc);
                    const float L  = flog2(fmaxf(xr - xj, 1.0f));
                    pacc += fexp2(-fmaf(c, em, a) * L);
                }
                part_lds[wid - 1][J][lane] += pacc;
            }
        } else if (J > 0) {
            // ---- wave 0: deferred epilogue of block J-1 (overlaps helpers' panel)
            const int i = ((J - 1) << 6) | lane;
            if (i >= 1) {
                const float q = k1 - k2 * flog2(clean);
                out[(i - 1) * BATCH + b] = 1.0f / (1.0f + fexp2(q));
            }
        }
        __syncthreads();  // panel partials ready / expm consumed

        if (wid == 0) {
            // ---- merge off-diagonal partials for row block J
            float acc = 0.0f;
#pragma unroll
            for (int hh = 0; hh < NH; ++hh) acc += part_lds[hh][J][lane];

            const float xd = x[J];
            __builtin_amdgcn_s_setprio(3);
            // ---- sequential diagonal: 3-dep chain (mul -> exp2 -> fmac)
#pragma unroll
            for (int jl = 0; jl < 64; ++jl) {
                const float sj = bcast_f(xd, jl);                 // off-chain
                const float L  = flog2(fmaxf(xd - sj, 1.0f));     // off-chain
                const float A  = fexp2(-a * L);                   // off-chain
                const float M  = -c * L;                          // off-chain
                const float em = bcast_f(acc, jl);                // chain
                acc = fmaf(A, fexp2(M * em), acc);                // chain
            }
            __builtin_amdgcn_s_setprio(0);
            clean = acc - (float)(64 - lane);
            expm_lds[(J << 6) | lane] = clean;                    // publish
        } else if (J > 0) {
            // ---- deep: col block J-1 -> row blocks J+1..7 (overlaps diag)
            for (int R = J + 1; R < 8; ++R) {
                const float xr = x[R];
                float pacc = 0.0f;
                for (int jc = wid - 1; jc < 64; jc += NH) {
                    const float em = bcast_f(evec, jc);
                    const float xj = bcast_f(x[J - 1], jc);
                    const float L  = flog2(fmaxf(xr - xj, 1.0f));
                    pacc += fexp2(-fmaf(c, em, a) * L);
                }
                part_lds[wid - 1][R][lane] += pacc;
            }
        }
        __syncthreads();  // expm block J published; deep writes done
    }

    // ---- final epilogue: block 7
    if (wid == 0) {
        const int i = (7 << 6) | lane;   // 448..511, all >= 1
        const float q = k1 - k2 * flog2(clean);
        out[(i - 1) * BATCH + b] = 1.0f / (1.0f + fexp2(q));
    }
}

extern "C" void kernel_launch(void* const* d_in, const int* in_sizes, int n_in,
                              void* d_out, int out_size, void* d_ws, size_t ws_size,
                              hipStream_t stream) {
    const float* sp = (const float*)d_in[0];  // [512, 256, 1] f32
    const float* w  = (const float*)d_in[1];  // [5] f32
    float* out = (float*)d_out;               // [511, 256, 1] f32
    (void)in_sizes; (void)n_in; (void)out_size; (void)d_ws; (void)ws_size;

    act_r_kernel<<<dim3(BATCH), dim3(512), 0, stream>>>(sp, w, out);
}

// Round 6
// 79.992 us; speedup vs baseline: 1.1032x; 1.1032x over previous
//
#include <hip/hip_runtime.h>

#define SEQ   512
#define BATCH 256
#define NH    7   // helper waves (waves 1..7)

// Uniform-index lane broadcast via v_readlane (index wave-uniform, may be runtime).
__device__ __forceinline__ float bcast_f(float v, int srcLane) {
    return __int_as_float(__builtin_amdgcn_readlane(__float_as_int(v), srcLane));
}
// gfx950: v_log_f32 is log2, v_exp_f32 is exp2.
__device__ __forceinline__ float flog2(float x) { return __builtin_amdgcn_logf(x); }
__device__ __forceinline__ float fexp2(float x) { return __builtin_amdgcn_exp2f(x); }

// One block (512 threads = 8 waves) per batch column.
// Phase J: wave 0 runs the serial 64-step diagonal of block J; helpers apply
// published column block J-1 to row block J ("panel", before the mid barrier)
// and row blocks J+1..7 ("deep", overlapping the diagonal). All inner loops
// are register-only: per phase each wave loads xjvec/evec (one coalesced LDS
// read each) and broadcasts per-column via v_readlane. NO dynamically-indexed
// register arrays (the R5 scratch-spill bug).
//
// Maskless diag trick: lanes i <= jl give d=1 -> L=0 -> A=1, M=0 -> term = 1.0
// exactly; the carry readlane at step jl reads lane jl before its first
// contamination (lane jl is only polluted by steps >= jl); subtract (64-lane)
// once at the end.
__global__ void __launch_bounds__(512, 1)
act_r_kernel(const float* __restrict__ sp, const float* __restrict__ w,
             float* __restrict__ out) {
    __shared__ float x_lds[SEQ];
    __shared__ float expm_lds[SEQ];
    __shared__ float part_lds[NH][8][64];   // [helper][row block][lane]

    const int b    = blockIdx.x;
    const int tid  = threadIdx.x;
    const int wid  = tid >> 6;
    const int lane = tid & 63;

    const float a   = w[0];
    const float c   = w[1];
    const float s   = w[2];
    const float tau = w[3];
    const float h   = w[4];
    const float scale = 86400.0f * h;

    for (int k = tid; k < NH * 8 * 64; k += 512) ((float*)part_lds)[k] = 0.0f;
    x_lds[tid] = sp[tid * BATCH + b] * scale;
    __syncthreads();

    const float inv_ln2 = 1.4426950408889634f;
    const float k1 = tau / s * inv_ln2;
    const float k2 = 1.0f / s;

    float clean = 0.0f;   // wave0: deferred-epilogue value of previous block

    for (int J = 0; J < 8; ++J) {
        // Per-phase wave-wide vectors (one coalesced LDS read each).
        float evec = 0.0f, xjvec = 0.0f;
        if (J > 0) {
            evec  = expm_lds[((J - 1) << 6) | lane];
            xjvec = x_lds[((J - 1) << 6) | lane];
        }

        if (wid > 0) {
            // ---- panel: col block J-1 -> row block J (register-only)
            if (J > 0) {
                const float xr = x_lds[(J << 6) | lane];
                float pacc = 0.0f;
#pragma unroll
                for (int k = 0; k < 10; ++k) {
                    const int  jc = (wid - 1) + k * NH;
                    const bool on = (jc < 64);
                    const int  js = on ? jc : 0;
                    const float em = bcast_f(evec, js);
                    const float xj = bcast_f(xjvec, js);
                    const float L  = flog2(fmaxf(xr - xj, 1.0f));
                    const float t  = fexp2(-fmaf(c, em, a) * L);
                    pacc += on ? t : 0.0f;
                }
                part_lds[wid - 1][J][lane] += pacc;
            }
        } else if (J > 0) {
            // ---- wave 0: deferred epilogue of block J-1 (overlaps panel)
            const int i = ((J - 1) << 6) | lane;
            if (i >= 1) {
                const float q = k1 - k2 * flog2(clean);
                out[(i - 1) * BATCH + b] = 1.0f / (1.0f + fexp2(q));
            }
        }
        __syncthreads();  // panel partials for row block J ready

        if (wid == 0) {
            // ---- merge off-diagonal partials for row block J
            float acc = 0.0f;
#pragma unroll
            for (int hh = 0; hh < NH; ++hh) acc += part_lds[hh][J][lane];

            const float xd = x_lds[(J << 6) | lane];
            // ---- sequential diagonal: chain = readlane -> mul -> exp2 -> fmac
#pragma unroll
            for (int jl = 0; jl < 64; ++jl) {
                const float sj = bcast_f(xd, jl);               // off-chain
                const float L  = flog2(fmaxf(xd - sj, 1.0f));   // off-chain
                const float A  = fexp2(-a * L);                 // off-chain
                const float M  = -c * L;                        // off-chain
                const float em = bcast_f(acc, jl);              // chain
                acc = fmaf(A, fexp2(M * em), acc);              // chain
            }
            clean = acc - (float)(64 - lane);
            expm_lds[(J << 6) | lane] = clean;                  // publish
        } else if (J > 0) {
            // ---- deep: col block J-1 -> row blocks J+1..7 (overlaps diag)
            for (int R = J + 1; R < 8; ++R) {
                const float xr = x_lds[(R << 6) | lane];
                float pacc = 0.0f;
#pragma unroll
                for (int k = 0; k < 10; ++k) {
                    const int  jc = (wid - 1) + k * NH;
                    const bool on = (jc < 64);
                    const int  js = on ? jc : 0;
                    const float em = bcast_f(evec, js);
                    const float xj = bcast_f(xjvec, js);
                    const float L  = flog2(fmaxf(xr - xj, 1.0f));
                    const float t  = fexp2(-fmaf(c, em, a) * L);
                    pacc += on ? t : 0.0f;
                }
                part_lds[wid - 1][R][lane] += pacc;
            }
        }
        __syncthreads();  // expm block J published; deep writes done
    }

    // ---- final epilogue: block 7
    if (wid == 0) {
        const int i = (7 << 6) | lane;   // 448..511, all >= 1
        const float q = k1 - k2 * flog2(clean);
        out[(i - 1) * BATCH + b] = 1.0f / (1.0f + fexp2(q));
    }
}

extern "C" void kernel_launch(void* const* d_in, const int* in_sizes, int n_in,
                              void* d_out, int out_size, void* d_ws, size_t ws_size,
                              hipStream_t stream) {
    const float* sp = (const float*)d_in[0];  // [512, 256, 1] f32
    const float* w  = (const float*)d_in[1];  // [5] f32
    float* out = (float*)d_out;               // [511, 256, 1] f32
    (void)in_sizes; (void)n_in; (void)out_size; (void)d_ws; (void)ws_size;

    act_r_kernel<<<dim3(BATCH), dim3(512), 0, stream>>>(sp, w, out);
}

// Round 7
// 79.688 us; speedup vs baseline: 1.1074x; 1.0038x over previous
//
#include <hip/hip_runtime.h>

#define SEQ   512
#define BATCH 256
#define NH    7   // helper waves (waves 1..7)

// Uniform-index lane broadcast via v_readlane (SGPR/imm index).
__device__ __forceinline__ float bcast_f(float v, int srcLane) {
    return __int_as_float(__builtin_amdgcn_readlane(__float_as_int(v), srcLane));
}
// gfx950: v_log_f32 is log2, v_exp_f32 is exp2.
__device__ __forceinline__ float flog2(float x) { return __builtin_amdgcn_logf(x); }
__device__ __forceinline__ float fexp2(float x) { return __builtin_amdgcn_exp2f(x); }
// Barrier draining only LDS ops (lgkmcnt). __syncthreads() also drains
// vmcnt(0), putting outstanding global stores on the serial path.
__device__ __forceinline__ void lds_barrier() {
    __asm__ __volatile__("s_waitcnt lgkmcnt(0)\ns_barrier" ::: "memory");
}

// 10-column (predicated) panel contribution: rows in lanes, columns jc =
// start..start+cnt-1 of column block (evec/xjvec hold expm/x of that block).
__device__ __forceinline__ float panel_terms(float xr, float evec, float xjvec,
                                             int start, int cnt, float a, float c) {
    float pacc = 0.0f;
#pragma unroll
    for (int k = 0; k < 10; ++k) {
        const int jc = start + k;                  // wave-uniform runtime index
        const float em = bcast_f(evec, jc);
        const float xj = bcast_f(xjvec, jc);
        const float L  = flog2(fmaxf(xr - xj, 1.0f));
        const float t  = fexp2(-fmaf(c, em, a) * L);
        pacc += (k < cnt) ? t : 0.0f;
    }
    return pacc;
}

// One block (512 threads = 8 waves) per batch column. Phase J: wave 0 runs the
// serial 64-step diagonal of block J (single-exp chain); helpers apply column
// block J-1 to row block J (panel, pre-barrier) and row blocks J+1..7 (deep,
// overlapping the diagonal). Helper wid4 shares SIMD0 with wave0 and takes 4
// columns instead of 10. All inner loops register-only via v_readlane.
// Maskless diag: lanes i <= jl give L=0 -> term=1.0 exactly; carry readlane at
// step jl precedes lane jl's first contamination; subtract (64-lane) once.
__global__ void __launch_bounds__(512, 1)
act_r_kernel(const float* __restrict__ sp, const float* __restrict__ w,
             float* __restrict__ out) {
    __shared__ float x_lds[SEQ];
    __shared__ float expm_lds[SEQ];
    __shared__ float part_lds[NH][8][64];   // [helper][row block][lane]

    const int b    = blockIdx.x;
    const int tid  = threadIdx.x;
    const int wid  = tid >> 6;
    const int lane = tid & 63;

    const float a   = w[0];
    const float c   = w[1];
    const float s   = w[2];
    const float tau = w[3];
    const float h   = w[4];
    const float scale = 86400.0f * h;

    // Column split: wid4 (co-resident with wave0 on SIMD0) gets 4 cols.
    const int start = (wid - 1) * 10 - ((wid > 4) ? 6 : 0);  // 0,10,20,30,34,44,54
    const int cnt   = (wid == 4) ? 4 : 10;

    for (int k = tid; k < NH * 8 * 64; k += 512) ((float*)part_lds)[k] = 0.0f;
    x_lds[tid] = sp[tid * BATCH + b] * scale;
    lds_barrier();

    for (int J = 0; J < 8; ++J) {
        float evec = 0.0f, xjvec = 0.0f;
        if (J > 0) {
            evec  = expm_lds[((J - 1) << 6) | lane];
            xjvec = x_lds[((J - 1) << 6) | lane];
        }

        if (wid > 0 && J > 0) {
            // ---- panel: col block J-1 -> row block J
            const float xr = x_lds[(J << 6) | lane];
            part_lds[wid - 1][J][lane] += panel_terms(xr, evec, xjvec, start, cnt, a, c);
        }
        lds_barrier();  // panel partials for row block J ready

        if (wid == 0) {
            // ---- merge off-diagonal partials for row block J
            float acc = 0.0f;
#pragma unroll
            for (int hh = 0; hh < NH; ++hh) acc += part_lds[hh][J][lane];

            const float xd = x_lds[(J << 6) | lane];
            // ---- serial diagonal: chain = readlane -> fma -> exp2 -> add
#pragma unroll
            for (int jl = 0; jl < 64; ++jl) {
                const float sj  = bcast_f(xd, jl);               // off-chain
                const float L   = flog2(fmaxf(xd - sj, 1.0f));   // off-chain
                const float nAL = -a * L;                        // off-chain
                const float nCL = -c * L;                        // off-chain
                const float em  = bcast_f(acc, jl);              // chain
                acc += fexp2(fmaf(nCL, em, nAL));                // chain
            }
            expm_lds[(J << 6) | lane] = acc - (float)(64 - lane);  // publish clean
        } else if (J > 0 && J < 7) {
            // ---- deep: col block J-1 -> row blocks J+1..7 (overlaps diag)
            float xr = x_lds[((J + 1) << 6) | lane];
            for (int R = J + 1; R < 8; ++R) {
                const int Rn = (R < 7) ? R + 1 : R;              // prefetch
                const float xr_next = x_lds[(Rn << 6) | lane];
                part_lds[wid - 1][R][lane] += panel_terms(xr, evec, xjvec, start, cnt, a, c);
                xr = xr_next;
            }
        }
        lds_barrier();  // expm block J published; deep writes done
    }

    // ---- epilogue: all 512 threads, one output each (i = tid, skip 0)
    if (tid >= 1) {
        const float inv_ln2 = 1.4426950408889634f;
        const float q = tau / s * inv_ln2 - flog2(expm_lds[tid]) / s;
        out[(tid - 1) * BATCH + b] = 1.0f / (1.0f + fexp2(q));
    }
}

extern "C" void kernel_launch(void* const* d_in, const int* in_sizes, int n_in,
                              void* d_out, int out_size, void* d_ws, size_t ws_size,
                              hipStream_t stream) {
    const float* sp = (const float*)d_in[0];  // [512, 256, 1] f32
    const float* w  = (const float*)d_in[1];  // [5] f32
    float* out = (float*)d_out;               // [511, 256, 1] f32
    (void)in_sizes; (void)n_in; (void)out_size; (void)d_ws; (void)ws_size;

    act_r_kernel<<<dim3(BATCH), dim3(512), 0, stream>>>(sp, w, out);
}